// Round 1
// 76.441 us; speedup vs baseline: 1.0326x; 1.0326x over previous
//
#include <hip/hip_runtime.h>
#include <hip/hip_bf16.h>
#include <math.h>

#define BATCH 8192
#define NF 512
#define NL 1024
#define ATOMS 513

typedef float float4v __attribute__((ext_vector_type(4)));
typedef int int4v __attribute__((ext_vector_type(4)));
typedef long long2v __attribute__((ext_vector_type(2)));

#define LOG2E 1.44269504088896340736f

// fp32 -> fp8 e4m3 (OCP) byte via HW pack instruction
__device__ __forceinline__ unsigned char f2fp8(float x) {
    return (unsigned char)(__builtin_amdgcn_cvt_pk_fp8_f32(x, x, 0, false) & 0xff);
}

// async 16B/lane global->LDS: lane i lands at ldsbase + i*16
__device__ __forceinline__ void load_lds16(const void* g, void* ldsbase) {
    __builtin_amdgcn_global_load_lds(
        (const __attribute__((address_space(1))) unsigned int*)g,
        (__attribute__((address_space(3))) unsigned int*)ldsbase,
        16, 0, 0);
}

// Fragment-packed layouts (kpair-interleaved):
//   Xp[rt (512)][kp (8)][lane (64)][16B]   rt = row/16
//   Wp[lt  (64)][kp (8)][lane (64)][16B]   lt = leaf/16
// lane = quad*16 + l16. bytes[half*8 + b] = M[rt*16 + l16][(2kp+half)*32 + quad*8 + b]

#define N_CONVERT_BLOCKS 512   // BATCH/16
#define N_SOFTMAX_BLOCKS 1024
#define N_ZERO_BLOCKS    33    // ceil((8192 + 64)/256)

// ---------------- Kernel 1: fused prep (convert-pack + softmax-pack + zero-init) ----------------
__global__ void prep_kernel(const float* __restrict__ X,
                            const float* __restrict__ logits,
                            unsigned char* __restrict__ Xp,
                            unsigned char* __restrict__ Wp,
                            float* __restrict__ bias,
                            float* __restrict__ sumexp,
                            int* __restrict__ cnt) {
    int bi = blockIdx.x;
    int t  = threadIdx.x;

    if (bi < N_CONVERT_BLOCKS) {
        // ---- role A: X fp32 -> fp8 packed into Xp fragment order ----
        __shared__ unsigned char tile[16 * 512];   // 8 KB, [row][k]
        int rt = bi;
        const float* base = X + (size_t)rt * 16 * 512;
#pragma unroll
        for (int i = 0; i < 8; ++i) {
            float4v v = *reinterpret_cast<const float4v*>(base + (size_t)i * 1024 + t * 4);
            int w = __builtin_amdgcn_cvt_pk_fp8_f32(v[0], v[1], 0, false);
            w = __builtin_amdgcn_cvt_pk_fp8_f32(v[2], v[3], w, true);
            reinterpret_cast<int*>(tile)[i * 256 + t] = w;
        }
        __syncthreads();
        int kp = t >> 5, j = t & 31;
#pragma unroll
        for (int e = 0; e < 2; ++e) {
            int ln = 2 * j + e;
            int l16 = ln & 15, quad = ln >> 4;
            const int* s0 = reinterpret_cast<const int*>(tile + l16 * 512 + (2 * kp) * 32 + quad * 8);
            const int* s1 = reinterpret_cast<const int*>(tile + l16 * 512 + (2 * kp + 1) * 32 + quad * 8);
            int4v o = (int4v){s0[0], s0[1], s1[0], s1[1]};
            *reinterpret_cast<int4v*>(Xp + (((size_t)rt * 8 + kp) * 64 + ln) * 16) = o;
        }
        return;
    }

    if (bi < N_CONVERT_BLOCKS + N_SOFTMAX_BLOCKS) {
        // ---- role B: per-leaf softmax; W' = 512*w packed into Wp ----
        int l = bi - N_CONVERT_BLOCKS;
        int wave = t >> 6, lane = t & 63;
        const float* row = logits + (size_t)l * ATOMS;
        float v0 = row[t];
        float v1 = row[t + 256];
        float v2 = (t == 0) ? row[512] : -1e30f;

        __shared__ float red[8];
        float m = fmaxf(fmaxf(v0, v1), v2);
#pragma unroll
        for (int o = 32; o > 0; o >>= 1) m = fmaxf(m, __shfl_xor(m, o, 64));
        if (lane == 0) red[wave] = m;
        __syncthreads();
        float mx = fmaxf(fmaxf(red[0], red[1]), fmaxf(red[2], red[3]));

        float e0 = __expf(v0 - mx);
        float e1 = __expf(v1 - mx);
        float e2 = (t == 0) ? __expf(v2 - mx) : 0.f;
        float s = e0 + e1 + e2;
#pragma unroll
        for (int o = 32; o > 0; o >>= 1) s += __shfl_xor(s, o, 64);
        if (lane == 0) red[4 + wave] = s;
        __syncthreads();
        float inv = 1.f / (red[4] + red[5] + red[6] + red[7]);
        float inv512 = inv * 512.f;   // keep fp8 near 1.0 (out of subnormal range)

        auto wp_off = [](int l_, int k_) -> size_t {
            int lt = l_ >> 4, l16_ = l_ & 15;
            int ks = k_ >> 5, kp_ = ks >> 1, half = ks & 1;
            int quad_ = (k_ >> 3) & 3, byt = k_ & 7;
            return ((size_t)((lt * 8 + kp_) * 64) + quad_ * 16 + l16_) * 16 + half * 8 + byt;
        };

        if (t == 0) {
            bias[l] = e0 * inv * LOG2E;              // atom 0, pre-scaled by log2e for exp2 epilogue
            Wp[wp_off(l, 511)] = f2fp8(e2 * inv512); // atom 512 -> k=511
        } else {
            Wp[wp_off(l, t - 1)] = f2fp8(e0 * inv512);   // atoms 1..255 -> k=0..254
        }
        Wp[wp_off(l, t + 255)] = f2fp8(e1 * inv512);     // atoms 256..511 -> k=255..510
        return;
    }

    // ---- role C: zero sumexp accumulators + arrival counters (ws poisoned 0xAA) ----
    int i = (bi - N_CONVERT_BLOCKS - N_SOFTMAX_BLOCKS) * 256 + t;
    if (i < BATCH) sumexp[i] = 0.f;
    else { int j = i - BATCH; if (j < 64) cnt[j] = 0; }
}

// ---------------- Kernel 2: fp8 MFMA GEMM + fence-free fused logsumexp finalize ----------------
// Grid: 512 blocks. XCD-locality remap: lg = bid>>6, rsb = bid&63 so that
// XCD = bid%8 = rsb%8 -> the 8 lg-blocks sharing one rsb (its 64KB A panel,
// its sumexp[rsb*128..] atomics, and its finalizer) all land on ONE XCD.
// (Old mapping put them on 8 different XCDs: each XCD pulled ~all of Xp (4MB)
// into its private L2 => ~32MB of L2-miss traffic vs ~8MB now.)
// Wave: 32 rows x 128 leaves. B panel (64 KB) staged to LDS once; ALL 16 A
// fragments (64 VGPRs) are preloaded before the stage barrier so the K-loop
// is pure ds_read_b128 + MFMA (no global/vmcnt stalls on the MFMA path).
// Finalize protocol (NO fences — R4 showed agent ACQ_REL fences cost ~19us):
// relaxed device atomicAdds into sumexp; __syncthreads' implicit vmcnt(0)
// drain orders them before the relaxed arrival-counter bump; 8th arrival
// reads totals via atomicAdd(p, 0.0f) RMWs (same coherent point) and writes out.
__global__ __launch_bounds__(256, 2)
void gemm_lse_kernel(const unsigned char* __restrict__ Xp,
                     const unsigned char* __restrict__ Wp,
                     const float* __restrict__ bias,
                     float* __restrict__ sumexp,
                     int* __restrict__ cnt,
                     float* __restrict__ out) {
    __shared__ unsigned char Bl[64 * 1024];   // whole B panel, fragment order
    __shared__ int lastFlag;

    int tid  = threadIdx.x;
    int wave = tid >> 6;
    int lane = tid & 63;
    int quad = lane >> 4;
    int l16  = lane & 15;

    int lg  = blockIdx.x >> 6;   // leaf group: leaves [lg*128, +128)
    int rsb = blockIdx.x & 63;   // row superblock: rows [rsb*128, +128); rsb%8 = XCD

    // one-time B panel stage: wave w covers bytes [w*16K, w*16K+16K)
    {
        const unsigned char* gb = Wp + (size_t)lg * 65536 + wave * 16384 + lane * 16;
        unsigned char* lb = Bl + wave * 16384;   // wave-uniform LDS base
#pragma unroll
        for (int j = 0; j < 16; ++j)
            load_lds16(gb + j * 1024, lb + j * 1024);
    }

    // A fragment pointer (per-lane): rowtiles rt = rsb*8 + wave*2 + mt
    const unsigned char* pa = Xp + ((size_t)(rsb * 8 + wave * 2) * 8) * 1024 + lane * 16;

    // preload ALL 16 A fragments (64 VGPRs) — in flight during the B stage;
    // the pre-K-loop barrier drains both together.
    long2v af[2][8];
#pragma unroll
    for (int mt = 0; mt < 2; ++mt)
#pragma unroll
        for (int kp = 0; kp < 8; ++kp)
            af[mt][kp] = *reinterpret_cast<const long2v*>(pa + (size_t)mt * 8192 + kp * 1024);

    // bias prefetch (in flight during the B stage); already scaled by log2e
    float bl[8];
#pragma unroll
    for (int nt = 0; nt < 8; ++nt)
        bl[nt] = bias[lg * 128 + nt * 16 + l16];

    float4v acc[2][8];
#pragma unroll
    for (int mt = 0; mt < 2; ++mt)
#pragma unroll
        for (int nt = 0; nt < 8; ++nt)
            acc[mt][nt] = (float4v){0.f, 0.f, 0.f, 0.f};

    __syncthreads();   // B panel resident (drains the global_load_lds + A prefetch)

#pragma unroll
    for (int kp = 0; kp < 8; ++kp) {
        long2v bf[8];
#pragma unroll
        for (int nt = 0; nt < 8; ++nt)
            bf[nt] = *reinterpret_cast<const long2v*>(Bl + (nt * 8 + kp) * 1024 + lane * 16);

#pragma unroll
        for (int mt = 0; mt < 2; ++mt)
#pragma unroll
            for (int nt = 0; nt < 8; ++nt) {
                acc[mt][nt] = __builtin_amdgcn_mfma_f32_16x16x32_fp8_fp8(
                    af[mt][kp][0], bf[nt][0], acc[mt][nt], 0, 0, 0);
                acc[mt][nt] = __builtin_amdgcn_mfma_f32_16x16x32_fp8_fp8(
                    af[mt][kp][1], bf[nt][1], acc[mt][nt], 0, 0, 0);
            }
    }

    // Epilogue: c*log2e = acc*(log2e/512) + biasL2; sum exp2 over this wave's 128 leaves
    const float C1 = 0.001953125f * LOG2E;
    float ps[2][4];
#pragma unroll
    for (int mt = 0; mt < 2; ++mt)
#pragma unroll
        for (int r = 0; r < 4; ++r) ps[mt][r] = 0.f;

#pragma unroll
    for (int nt = 0; nt < 8; ++nt)
#pragma unroll
        for (int mt = 0; mt < 2; ++mt)
#pragma unroll
            for (int r = 0; r < 4; ++r)
                ps[mt][r] += exp2f(fmaf(acc[mt][nt][r], C1, bl[nt]));

    // reduce across the 16 columns (xor masks < 16 stay within the quad group)
#pragma unroll
    for (int m = 1; m < 16; m <<= 1)
#pragma unroll
        for (int mt = 0; mt < 2; ++mt)
#pragma unroll
            for (int r = 0; r < 4; ++r)
                ps[mt][r] += __shfl_xor(ps[mt][r], m, 64);

    // per-wave direct relaxed atomics (row ownership disjoint across waves):
    // row-in-superblock = wave*32 + mt*16 + quad*4 + r  — no LDS round-trip needed
    if (l16 == 0) {
#pragma unroll
        for (int mt = 0; mt < 2; ++mt)
#pragma unroll
            for (int r = 0; r < 4; ++r)
                __hip_atomic_fetch_add(&sumexp[rsb * 128 + wave * 32 + mt * 16 + quad * 4 + r],
                                       ps[mt][r],
                                       __ATOMIC_RELAXED, __HIP_MEMORY_SCOPE_AGENT);
    }
    __syncthreads();   // implicit vmcnt(0): this block's adds are ack'd

    if (tid == 0) {
        int old = __hip_atomic_fetch_add(&cnt[rsb], 1,
                                         __ATOMIC_RELAXED, __HIP_MEMORY_SCOPE_AGENT);
        lastFlag = (old == 7);
    }
    __syncthreads();

    if (lastFlag && tid < 128) {
        // RMW read at the same coherent point the adds landed at
        float s = __hip_atomic_fetch_add(&sumexp[rsb * 128 + tid], 0.0f,
                                         __ATOMIC_RELAXED, __HIP_MEMORY_SCOPE_AGENT);
        out[rsb * 128 + tid] = logf(s);
    }
}

extern "C" void kernel_launch(void* const* d_in, const int* in_sizes, int n_in,
                              void* d_out, int out_size, void* d_ws, size_t ws_size,
                              hipStream_t stream) {
    const float* X      = (const float*)d_in[0];   // (8192, 512) fp32
    const float* logits = (const float*)d_in[1];   // (1024, 513) fp32
    float* out = (float*)d_out;                    // (8192,) fp32

    char* ws = (char*)d_ws;
    unsigned char* Xp = (unsigned char*)ws;                                  // 4 MB
    unsigned char* Wp = (unsigned char*)(ws + (size_t)BATCH * NF);           // 512 KB
    float* bias   = (float*)(ws + (size_t)BATCH * NF + (size_t)NL * NF);     // 4 KB
    float* sumexp = (float*)((char*)bias + NL * sizeof(float));              // 32 KB
    int*   cnt    = (int*)((char*)sumexp + BATCH * sizeof(float));           // 256 B

    prep_kernel<<<N_CONVERT_BLOCKS + N_SOFTMAX_BLOCKS + N_ZERO_BLOCKS, 256, 0, stream>>>(
        X, logits, Xp, Wp, bias, sumexp, cnt);
    gemm_lse_kernel<<<(BATCH / 128) * (NL / 128), 256, 0, stream>>>(
        Xp, Wp, bias, sumexp, cnt, out);
}